// Round 18
// baseline (59.343 us; speedup 1.0000x reference)
//
#include <hip/hip_runtime.h>

#define LSEQ 2048
#define DIN  1330
#define NB   8
#define SPLITK 7
#define KCH 192          // 6*32; 7*192 = 1344
#define K1PAD 1344
#define NSTEP 6

typedef short bf16x8 __attribute__((ext_vector_type(8)));
typedef float f32x4  __attribute__((ext_vector_type(4)));

__device__ __forceinline__ float lsef(float a, float b) {
  float m = fmaxf(a, b);
  float d = fminf(a, b) - m;
  return m + log1pf(__expf(d));
}

__device__ __forceinline__ unsigned short f2bf(float f) {   // RNE
  unsigned int u = __float_as_uint(f);
  return (unsigned short)((u + 0x7FFFu + ((u >> 16) & 1u)) >> 16);
}

// ---------------- K0: w1 fp32 [k][h] -> w1T bf16 [h][K1PAD] (zero-padded) --------
__global__ __launch_bounds__(256) void k0_wt(
    const float* __restrict__ w1, unsigned short* __restrict__ w1T) {
  const int f = (blockIdx.x * 256 + threadIdx.x) * 4;   // 42 blocks * 1024 = 43008
  const int h = f / K1PAD, k = f % K1PAD;               // 1344 % 4 == 0
  ushort4 v;
  v.x = (k     < DIN) ? f2bf(w1[(long)(k)     * 32 + h]) : (unsigned short)0;
  v.y = (k + 1 < DIN) ? f2bf(w1[(long)(k + 1) * 32 + h]) : (unsigned short)0;
  v.z = (k + 2 < DIN) ? f2bf(w1[(long)(k + 2) * 32 + h]) : (unsigned short)0;
  v.w = (k + 3 < DIN) ? f2bf(w1[(long)(k + 3) * 32 + h]) : (unsigned short)0;
  *(ushort4*)(w1T + f) = v;
}

// ---------------- K1: p[s] = x[:,ks] @ w1[ks,:] via MFMA, zero-LDS ----------------
// v15: both MFMA frags loaded DIRECTLY to registers -- A: 2 guarded float4 x-loads
// + f2bf pack (lane: row=l&15, k=(l>>4)*8..+8); B: one 16B load from bf16 w1T
// (lane: h=l&15 / 16+l&15, same k-octet). No LDS, no barriers: r15-r17's
// block-step serialization (~2300cyc invariant) came from barrier convoys; here
// 7 fully-independent waves/SIMD round-robin over the ~900cyc HBM/L3 latency.
__global__ __launch_bounds__(256) void k1_mfma(
    const float* __restrict__ x, const unsigned short* __restrict__ w1T,
    float* __restrict__ p) {
  const int tid  = threadIdx.x;
  const int rb   = blockIdx.x / SPLITK;     // 0..255
  const int s    = blockIdx.x % SPLITK;
  const int k0   = s * KCH;

  const int wv   = tid >> 6;                // wave 0..3 -> 16-row strip
  const int lane = tid & 63;
  const int fr   = lane & 15;
  const int fg   = lane >> 4;

  const long row  = (long)rb * 64 + wv * 16 + fr;     // A row for this lane
  const float* ap = x + row * DIN;
  const unsigned short* bp0 = w1T + (long)fr * K1PAD;        // B0: h = fr
  const unsigned short* bp1 = w1T + (long)(16 + fr) * K1PAD; // B1: h = 16+fr

  f32x4 acc0 = {0.f, 0.f, 0.f, 0.f};
  f32x4 acc1 = {0.f, 0.f, 0.f, 0.f};

  #pragma unroll
  for (int t = 0; t < NSTEP; ++t) {
    const int ka = k0 + t * 32 + fg * 8;
    float4 u, v;
    if (ka + 7 < DIN) {
      u = *(const float4*)(ap + ka);
      v = *(const float4*)(ap + ka + 4);
    } else {
      u = make_float4(0.f, 0.f, 0.f, 0.f);
      v = make_float4(0.f, 0.f, 0.f, 0.f);
      if (ka     < DIN) u.x = ap[ka];
      if (ka + 1 < DIN) u.y = ap[ka + 1];
      if (ka + 2 < DIN) u.z = ap[ka + 2];
      if (ka + 3 < DIN) u.w = ap[ka + 3];
      if (ka + 4 < DIN) v.x = ap[ka + 4];
      if (ka + 5 < DIN) v.y = ap[ka + 5];
      if (ka + 6 < DIN) v.z = ap[ka + 6];
      if (ka + 7 < DIN) v.w = ap[ka + 7];
    }
    bf16x8 a;
    a[0] = (short)f2bf(u.x); a[1] = (short)f2bf(u.y);
    a[2] = (short)f2bf(u.z); a[3] = (short)f2bf(u.w);
    a[4] = (short)f2bf(v.x); a[5] = (short)f2bf(v.y);
    a[6] = (short)f2bf(v.z); a[7] = (short)f2bf(v.w);

    const bf16x8 b0 = *(const bf16x8*)(bp0 + ka);   // ka+8 <= 1344 = K1PAD
    const bf16x8 b1 = *(const bf16x8*)(bp1 + ka);

    acc0 = __builtin_amdgcn_mfma_f32_16x16x32_bf16(a, b0, acc0, 0, 0, 0);
    acc1 = __builtin_amdgcn_mfma_f32_16x16x32_bf16(a, b1, acc1, 0, 0, 0);
  }

  // C write: col = fr (acc0) / 16+fr (acc1), row = strip + fg*4 + i (m89 map)
  float* ps = p + (long)s * 524288 + ((long)rb * 64 + wv * 16 + fg * 4) * 32;
  #pragma unroll
  for (int i = 0; i < 4; ++i) {
    ps[(long)i * 32 + fr]      = acc0[i];
    ps[(long)i * 32 + 16 + fr] = acc1[i];
  }
}

// ---------------- K2: h = sum_s p[s]+b1; em = relu(conv1d(h)+cb)@w2+b2 ----------
__global__ __launch_bounds__(256) void k2_conv(
    const float* __restrict__ p, const float* __restrict__ b1,
    const float* __restrict__ cw, const float* __restrict__ cb,
    const float* __restrict__ w2, const float* __restrict__ b2,
    float* __restrict__ em) {
  const int g = blockIdx.x * 256 + threadIdx.x;   // 0..131071
  const int row  = g >> 3;
  const int isub = g & 7;
  const int i0   = isub << 2;
  const int li   = row & (LSEQ - 1);

  const float4* p4 = (const float4*)p;
  const float4 bv = ((const float4*)b1)[isub];
  float4 z; z.x = z.y = z.z = z.w = 0.f;

  auto hrow = [&](int r) -> float4 {
    float4 a = p4[(long)r * 8 + isub];
    #pragma unroll
    for (int s = 1; s < SPLITK; ++s) {
      float4 v = p4[(long)s * 131072 + (long)r * 8 + isub];
      a.x += v.x; a.y += v.y; a.z += v.z; a.w += v.w;
    }
    a.x += bv.x; a.y += bv.y; a.z += bv.z; a.w += bv.w;
    return a;
  };

  float4 hm = (li > 0)        ? hrow(row - 1) : z;
  float4 hc = hrow(row);
  float4 hp = (li < LSEQ - 1) ? hrow(row + 1) : z;

  float s[16];
  #pragma unroll
  for (int o = 0; o < 16; ++o) {
    const float4* wpq = (const float4*)(cw + o * 96 + i0 * 3);
    const float4 wa = wpq[0], wb = wpq[1], wc = wpq[2];
    s[o] = hm.x * wa.x + hc.x * wa.y + hp.x * wa.z
         + hm.y * wa.w + hc.y * wb.x + hp.y * wb.y
         + hm.z * wb.z + hc.z * wb.w + hp.z * wc.x
         + hm.w * wc.y + hc.w * wc.z + hp.w * wc.w;
  }
  #pragma unroll
  for (int o = 0; o < 16; ++o) {
    s[o] += __shfl_xor(s[o], 1, 8);
    s[o] += __shfl_xor(s[o], 2, 8);
    s[o] += __shfl_xor(s[o], 4, 8);
  }
  if (isub == 0) {
    float e0 = b2[0], e1 = b2[1];
    #pragma unroll
    for (int o = 0; o < 16; ++o) {
      float rr = fmaxf(s[o] + cb[o], 0.f);
      e0 += rr * w2[o * 2];
      e1 += rr * w2[o * 2 + 1];
    }
    float2 ev; ev.x = e0; ev.y = e1;
    *(float2*)(em + (long)row * 2) = ev;
  }
}

// ---------------- K3: per-batch CRF, role-split (16 blocks) ----------------
__global__ __launch_bounds__(256) void k3_crf(
    const float* __restrict__ em, const int* __restrict__ tokens_length,
    const int* __restrict__ labels, const float* __restrict__ start_trans,
    const float* __restrict__ end_trans, const float* __restrict__ trans,
    float* __restrict__ llh, float* __restrict__ out) {
  __shared__ float sem[LSEQ * 2];
  __shared__ unsigned char hist[LSEQ];
  __shared__ float4 mats[256];
  __shared__ float red[256];
  __shared__ unsigned char bmA[256], bmB[256];
  __shared__ int s_last;

  const int t = threadIdx.x;
  const int b = blockIdx.x & 7;
  const int role = blockIdx.x >> 3;
  const int len = tokens_length[b];
  const float t00 = trans[0], t01 = trans[1], t10 = trans[2], t11 = trans[3];
  const float st0 = start_trans[0], st1 = start_trans[1];
  const float en0 = end_trans[0], en1 = end_trans[1];
  const int* lab = labels + b * LSEQ;

  {
    const float4* src4 = (const float4*)(em + (long)b * LSEQ * 2);
    float4* dst4 = (float4*)sem;
    #pragma unroll
    for (int i = t; i < LSEQ * 2 / 4; i += 256) dst4[i] = src4[i];
    if (role == 1) {
      #pragma unroll
      for (int l = t; l < LSEQ; l += 256) hist[l] = 2;
    }
  }
  __syncthreads();

  int lo = t * 8; if (lo < 1) lo = 1;
  int hi = t * 8 + 8; if (hi > len) hi = len;

  if (role == 0) {
    float sc = 0.f;
    {
      const int base = t * 8;
      #pragma unroll
      for (int k = 0; k < 8; ++k) {
        int l = base + k;
        if (l >= 1 && l < len) {
          int lp = lab[l - 1], lc = lab[l];
          sc += trans[lp * 2 + lc] + sem[2 * l + lc];
        }
      }
    }
    red[t] = sc;

    {
      float p00 = 0.f, p01 = -1e30f, p10 = -1e30f, p11 = 0.f;
      for (int l = lo; l < hi; ++l) {
        float e0 = sem[2 * l], e1 = sem[2 * l + 1];
        float n00 = lsef(p00 + t00, p01 + t10) + e0;
        float n01 = lsef(p00 + t01, p01 + t11) + e1;
        float n10 = lsef(p10 + t00, p11 + t10) + e0;
        float n11 = lsef(p10 + t01, p11 + t11) + e1;
        p00 = n00; p01 = n01; p10 = n10; p11 = n11;
      }
      float4 m; m.x = p00; m.y = p01; m.z = p10; m.w = p11; mats[t] = m;
    }
    __syncthreads();

    for (int n = 128; n >= 1; n >>= 1) {
      if (t < n) red[t] += red[t + n];
      __syncthreads();
    }
    for (int n = 128; n >= 1; n >>= 1) {
      float4 A, B; const bool act = (t < n);
      if (act) { A = mats[2 * t]; B = mats[2 * t + 1]; }
      __syncthreads();
      if (act) {
        float4 C;
        C.x = lsef(A.x + B.x, A.y + B.z);
        C.y = lsef(A.x + B.y, A.y + B.w);
        C.z = lsef(A.z + B.x, A.w + B.z);
        C.w = lsef(A.z + B.y, A.w + B.w);
        mats[t] = C;
      }
      __syncthreads();
    }

    if (t == 0) {
      int lab0 = lab[0];
      float s0 = (lab0 ? st1 : st0) + sem[lab0];
      int labe = lab[len - 1];
      float score = red[0] + s0 + (labe ? en1 : en0);
      float4 M = mats[0];
      float a00 = st0 + sem[0], a01 = st1 + sem[1];
      float af0 = lsef(a00 + M.x, a01 + M.z);
      float af1 = lsef(a00 + M.y, a01 + M.w);
      float norm = lsef(af0 + en0, af1 + en1);
      llh[b] = score - norm;
    }
    return;
  }

  // role 1: Viterbi forward max-plus chunk scan
  {
    float q00 = 0.f, q01 = -1e30f, q10 = -1e30f, q11 = 0.f;
    for (int l = lo; l < hi; ++l) {
      float e0 = sem[2 * l], e1 = sem[2 * l + 1];
      float n00 = fmaxf(q00 + t00, q01 + t10) + e0;
      float n01 = fmaxf(q00 + t01, q01 + t11) + e1;
      float n10 = fmaxf(q10 + t00, q11 + t10) + e0;
      float n11 = fmaxf(q10 + t01, q11 + t11) + e1;
      q00 = n00; q01 = n01; q10 = n10; q11 = n11;
    }
    float4 m; m.x = q00; m.y = q01; m.z = q10; m.w = q11; mats[t] = m;
  }
  __syncthreads();

  for (int off = 1; off < 256; off <<= 1) {
    float4 cur = mats[t];
    float4 prv;
    const bool has = (t >= off);
    if (has) prv = mats[t - off];
    __syncthreads();
    if (has) {
      float4 c;
      c.x = fmaxf(prv.x + cur.x, prv.y + cur.z);
      c.y = fmaxf(prv.x + cur.y, prv.y + cur.w);
      c.z = fmaxf(prv.z + cur.x, prv.w + cur.z);
      c.w = fmaxf(prv.z + cur.y, prv.w + cur.w);
      mats[t] = c;
    }
    __syncthreads();
  }

  {
    const float v00 = st0 + sem[0], v01 = st1 + sem[1];
    float vp0, vp1;
    if (t == 0) { vp0 = v00; vp1 = v01; }
    else {
      float4 E = mats[t - 1];
      vp0 = fmaxf(v00 + E.x, v01 + E.z);
      vp1 = fmaxf(v00 + E.y, v01 + E.w);
    }
    for (int l = lo; l < hi; ++l) {
      float e0 = sem[2 * l], e1 = sem[2 * l + 1];
      float s00 = vp0 + t00, s10 = vp1 + t10;
      float s01 = vp0 + t01, s11 = vp1 + t11;
      hist[l] = (unsigned char)((s00 >= s10 ? 0 : 1) | ((s01 >= s11 ? 0 : 1) << 1));
      vp0 = fmaxf(s00, s10) + e0;
      vp1 = fmaxf(s01, s11) + e1;
    }
    if (hi == len && lo < hi)
      s_last = (vp0 + en0 >= vp1 + en1) ? 0 : 1;
    if (t == 0 && len == 1)
      s_last = (v00 + en0 >= v01 + en1) ? 0 : 1;
  }
  __syncthreads();
  const int last = s_last;

  {
    int blo = (t == 0) ? 1 : t * 8;
    int bhi = t * 8 + 8;
    int m0 = 0, m1 = 1;
    for (int l = bhi - 1; l >= blo; --l) {
      int h = hist[l];
      m0 = (h >> m0) & 1;
      m1 = (h >> m1) & 1;
    }
    bmA[t] = (unsigned char)(m0 | (m1 << 1));
  }
  __syncthreads();
  {
    unsigned char* sarr = bmA; unsigned char* darr = bmB;
    for (int off = 1; off < 256; off <<= 1) {
      int a = sarr[t];
      int c = a;
      if (t + off < 256) {
        int bm = sarr[t + off];
        int c0 = (a >> (bm & 1)) & 1;
        int c1 = (a >> ((bm >> 1) & 1)) & 1;
        c = c0 | (c1 << 1);
      }
      darr[t] = (unsigned char)c;
      __syncthreads();
      unsigned char* tmp = sarr; sarr = darr; darr = tmp;
    }
    int xv = (t == 255) ? last : ((sarr[t + 1] >> last) & 1);
    int blo = (t == 0) ? 1 : t * 8;
    int bhi = t * 8 + 8;
    float* tout = out + 1 + b * LSEQ;
    for (int l = bhi - 1; l >= blo; --l) {
      xv = (hist[l] >> xv) & 1;
      int pidx = l - 1;
      tout[pidx] = (pidx < len) ? (float)xv : 0.0f;
    }
    if (t == 255) tout[LSEQ - 1] = ((LSEQ - 1) < len) ? (float)last : 0.0f;
  }
}

// ---------------- K4: deterministic final sum ----------------
__global__ void k4_final(const float* __restrict__ llh, float* __restrict__ out) {
  if (threadIdx.x == 0 && blockIdx.x == 0) {
    float s = 0.f;
    #pragma unroll
    for (int i = 0; i < NB; ++i) s += llh[i];
    out[0] = -s;
  }
}

extern "C" void kernel_launch(void* const* d_in, const int* in_sizes, int n_in,
                              void* d_out, int out_size, void* d_ws, size_t ws_size,
                              hipStream_t stream) {
  const float* x  = (const float*)d_in[0];
  const int*   tl = (const int*)d_in[1];
  const int*   lb = (const int*)d_in[2];
  const float* w1 = (const float*)d_in[3];
  const float* b1 = (const float*)d_in[4];
  const float* cw = (const float*)d_in[5];
  const float* cb = (const float*)d_in[6];
  const float* w2 = (const float*)d_in[7];
  const float* b2 = (const float*)d_in[8];
  const float* st = (const float*)d_in[9];
  const float* en = (const float*)d_in[10];
  const float* tr = (const float*)d_in[11];
  float* out = (float*)d_out;
  float* ws  = (float*)d_ws;

  float* p   = ws;                                   // 7 * 524288 floats (14 MB)
  float* em  = ws + (long)SPLITK * 524288;           // 32768 floats
  float* llh = em + 32768;                           // 8 floats
  unsigned short* w1T = (unsigned short*)(llh + 16); // 43008 ushorts (86 KB)

  hipLaunchKernelGGL(k0_wt, dim3(42), dim3(256), 0, stream, w1, w1T);
  hipLaunchKernelGGL(k1_mfma, dim3(256 * SPLITK), dim3(256), 0, stream, x, w1T, p);
  hipLaunchKernelGGL(k2_conv, dim3(512), dim3(256), 0, stream, p, b1, cw, cb, w2, b2, em);
  hipLaunchKernelGGL(k3_crf, dim3(16), dim3(256), 0, stream, em, tl, lb, st, en, tr, llh, out);
  hipLaunchKernelGGL(k4_final, dim3(1), dim3(64), 0, stream, llh, out);
}